// Round 10
// baseline (230.666 us; speedup 1.0000x reference)
//
#include <hip/hip_runtime.h>

typedef unsigned int u32;
typedef unsigned long long u64;

#define R_ROUNDS 64
#define HID 256
#define BATCH 16384
#define RPW 4   // batch rows per wave

// ---------------------------------------------------------------------------
// GF(2) reduction of the reference:
//   s' = (floor(s@M^T + n)) mod 2, s,n in {0,1}, M in {-1,0,1}
//      = parity(popcount(s & (M!=0) row)) XOR n        (-1 == 1 mod 2)
//
// pi-order: lane l owns output bits {4l..4l+3}; packed u64 word k of the
// state has bit l = vector bit (4l+k). Noise/state/out are float4 per lane.
//
// Round 10 = round-9 counted-drain skeleton with 2-ROUND PHASES:
//  - noise for a row is fetched as 2KB contiguous (rounds r,r+1 adjacent
//    in memory) -> half the DRAM page activations of the 1KB-granule
//    pattern (the suspected source of the 79%-of-stream ceiling).
//  - barriers halve (64 -> 33).
//  - per phase: {STAGE2 4 loads; LOADN2 8 loads; RUN; RUN;
//               s_waitcnt vmcnt(8); s_barrier; sched_barrier(0)}
//    Stage issued FIRST so vmcnt(8) retires exactly this phase's 4 stage
//    loads (L2-hit, ~300cyc, a full compute-phase in flight) and leaves
//    all 8 noise loads outstanding across the barrier (consumed next
//    phase via the compiler's own register wait, vmcnt(12) equivalent).
//    The HBM queue never drains.
//  - LDS: 2 x 16KB double-buffer (32KB) -> still 4 blocks/CU.
// ---------------------------------------------------------------------------

// Pack ternary matrices -> pi-ordered, round-transposed bitmasks in d_ws.
// Round r's 8KB block: u32 P[r*2048 + t*256 + l*4 + q] = u32 (4h+q) of
// mask row (4l+i), where t = 2i+h; row u32 layout [W0lo,W0hi,...,W3lo,W3hi],
// W_k bit l = (M[row][4l+k] != 0).   (Byte-identical to rounds 7/8/9.)
__global__ __launch_bounds__(256) void pack_matrices_kernel(
        const float* __restrict__ M, u32* __restrict__ P) {
    const int lane = threadIdx.x & 63;
    const int gw   = (int)((blockIdx.x * blockDim.x + threadIdx.x) >> 6); // row 0..16383
    const int r    = gw >> 8;      // round
    const int jj   = gw & 255;     // row within round
    const float4 v = *(const float4*)(M + (size_t)gw * HID + 4 * lane);
    const u64 b0 = __ballot(v.x != 0.0f);
    const u64 b1 = __ballot(v.y != 0.0f);
    const u64 b2 = __ballot(v.z != 0.0f);
    const u64 b3 = __ballot(v.w != 0.0f);
    if (lane < 8) {
        const int w = lane;                 // u32-in-row index 0..7
        u64 bb = b0;
        if ((w >> 1) == 1) bb = b1;
        if ((w >> 1) == 2) bb = b2;
        if ((w >> 1) == 3) bb = b3;
        const u32 val = (w & 1) ? (u32)(bb >> 32) : (u32)bb;
        const int t = 2 * (jj & 3) + (w >> 2);          // chunk index 0..7
        P[r * 2048 + t * 256 + (jj >> 2) * 4 + (w & 3)] = val;
    }
}

__global__ __launch_bounds__(256, 4) void tenshash_kernel(
        const float* __restrict__ state,
        const u32*  __restrict__ pA,
        const float* __restrict__ noise,
        float* __restrict__ out) {
    const int lane = threadIdx.x & 63;
    const int warp = threadIdx.x >> 6;
    const int wave = (int)(blockIdx.x * 4 + warp);
    const int row0 = wave * RPW;

    __shared__ u32 smem[2][4096];   // 2 x 16KB phase buffers (2 rounds each)

    // ---- init state (pi-order): S_k[rw] bit l = state bit (4l+k) ----
    u64 S0[RPW], S1[RPW], S2[RPW], S3[RPW];
#pragma unroll
    for (int rw = 0; rw < RPW; ++rw) {
        const float4 v = *(const float4*)(state + (size_t)(row0 + rw) * HID + 4 * lane);
        S0[rw] = __ballot(v.x != 0.0f);
        S1[rw] = __ballot(v.y != 0.0f);
        S2[rw] = __ballot(v.z != 0.0f);
        S3[rw] = __ballot(v.w != 0.0f);
    }

    const float* no_l = noise + (size_t)row0 * (R_ROUNDS * HID) + 4 * lane;

    // Stage rounds (q,q+1) = 16KB (transposed layout: LINEAR both sides):
    // 16 x 1KB chunks, each of the 4 waves stages 4 = 4 VMEM ops.
    auto STAGE2 = [&](int q, int b) {
        const char* g = (const char*)(pA + (size_t)q * 2048);
#pragma unroll
        for (int t = 4 * warp; t < 4 * warp + 4; ++t) {
            __builtin_amdgcn_global_load_lds(
                (const __attribute__((address_space(1))) void*)
                    (g + t * 1024 + lane * 16),
                (__attribute__((address_space(3))) void*)&smem[b][t * 256],
                16, 0, 0);
        }
    };
    // Noise rounds (q,q+1): per row a 2KB-contiguous pair of float4 loads
    // (adjacent 1KB wave-transactions -> same/adjacent DRAM page). 8 VMEM.
    auto LOADN2 = [&](float4* na, float4* nb, int q) {
#pragma unroll
        for (int rw = 0; rw < RPW; ++rw) {
            const float* base = no_l + (size_t)rw * (R_ROUNDS * HID) + q * HID;
            na[rw] = *(const float4*)base;
            nb[rw] = *(const float4*)(base + HID);
        }
    };
    // i-outer RUN (8 live mask VGPRs): chunk t at uint4 slot t*64+lane;
    // a0/a1 = the 8 u32s of mask row 4l+i.
    auto RUN = [&](const u32* base, const float4* n) {
        const uint4* p = (const uint4*)base;
        u64 ns0[RPW], ns1[RPW], ns2[RPW], ns3[RPW];
#pragma unroll
        for (int i = 0; i < 4; ++i) {
            const uint4 a0 = p[((2 * i) << 6) + lane];
            const uint4 a1 = p[((2 * i + 1) << 6) + lane];
            const u64 W0 = (u64)a0.x | ((u64)a0.y << 32);
            const u64 W1 = (u64)a0.z | ((u64)a0.w << 32);
            const u64 W2 = (u64)a1.x | ((u64)a1.y << 32);
            const u64 W3 = (u64)a1.z | ((u64)a1.w << 32);
#pragma unroll
            for (int rw = 0; rw < RPW; ++rw) {
                const float nfv = (i == 0) ? n[rw].x : (i == 1) ? n[rw].y
                                : (i == 2) ? n[rw].z : n[rw].w;
                const u32 c = (u32)__popcll(W0 & S0[rw]) + (u32)__popcll(W1 & S1[rw])
                            + (u32)__popcll(W2 & S2[rw]) + (u32)__popcll(W3 & S3[rw])
                            + (u32)nfv;                    // exact: nfv in {0.0,1.0}
                const u64 nb = __ballot((c & 1u) != 0);
                if (i == 0) ns0[rw] = nb; else if (i == 1) ns1[rw] = nb;
                else if (i == 2) ns2[rw] = nb; else ns3[rw] = nb;
            }
        }
#pragma unroll
        for (int rw = 0; rw < RPW; ++rw) {
            S0[rw] = ns0[rw]; S1[rw] = ns1[rw];
            S2[rw] = ns2[rw]; S3[rw] = ns3[rw];
        }
    };

    // Noise buffers: nX0 = even round of the phase, nX1 = odd round.
    float4 nA0[RPW], nA1[RPW], nB0[RPW], nB1[RPW];

    // ---- prologue: stage rounds 0,1 -> buf0; noise rounds 0,1 -> nA ----
    STAGE2(0, 0);                       // 4 VMEM (oldest)
    LOADN2(nA0, nA1, 0);                // 8 VMEM
    asm volatile("s_waitcnt vmcnt(8)" ::: "memory");  // retire the 4 stage
    __builtin_amdgcn_s_barrier();
    __builtin_amdgcn_sched_barrier(0);

#pragma unroll 1
    for (int r = 0; r < R_ROUNDS; r += 4) {
        // ---- phase A: rounds r, r+1 from buf0 / nA ----
        {
            int q = r + 2; if (q > 62) q = 62;          // even, redundant on tail
            STAGE2(q, 1);                               // 4 VMEM (issue FIRST)
            LOADN2(nB0, nB1, q);                        // 8 VMEM
        }
        RUN(&smem[0][0],    nA0);                       // round r
        RUN(&smem[0][2048], nA1);                       // round r+1
        asm volatile("s_waitcnt vmcnt(8)" ::: "memory");// retire phase's stage
        __builtin_amdgcn_s_barrier();
        __builtin_amdgcn_sched_barrier(0);

        // ---- phase B: rounds r+2, r+3 from buf1 / nB ----
        {
            int q = r + 4; if (q > 62) q = 62;
            STAGE2(q, 0);
            LOADN2(nA0, nA1, q);
        }
        RUN(&smem[1][0],    nB0);                       // round r+2
        RUN(&smem[1][2048], nB1);                       // round r+3
        asm volatile("s_waitcnt vmcnt(8)" ::: "memory");
        __builtin_amdgcn_s_barrier();
        __builtin_amdgcn_sched_barrier(0);
    }

    // ---- unpack final state, float4 stores ----
#pragma unroll
    for (int rw = 0; rw < RPW; ++rw) {
        float4 o;
        o.x = (float)((u32)(S0[rw] >> lane) & 1u);
        o.y = (float)((u32)(S1[rw] >> lane) & 1u);
        o.z = (float)((u32)(S2[rw] >> lane) & 1u);
        o.w = (float)((u32)(S3[rw] >> lane) & 1u);
        *(float4*)(out + (size_t)(row0 + rw) * HID + 4 * lane) = o;
    }
}

extern "C" void kernel_launch(void* const* d_in, const int* in_sizes, int n_in,
                              void* d_out, int out_size, void* d_ws, size_t ws_size,
                              hipStream_t stream) {
    const float* state = (const float*)d_in[0];
    const float* mats  = (const float*)d_in[1];
    const float* noise = (const float*)d_in[2];
    float* out         = (float*)d_out;
    u32* pA            = (u32*)d_ws;              // 512 KB packed masks

    pack_matrices_kernel<<<(R_ROUNDS * HID) / 4, 256, 0, stream>>>(mats, pA);

    const int blocks = (BATCH / RPW) / 4;         // 1024 blocks x 4 waves
    tenshash_kernel<<<blocks, 256, 0, stream>>>(state, pA, noise, out);
}

// Round 11
// 227.337 us; speedup vs baseline: 1.0146x; 1.0146x over previous
//
#include <hip/hip_runtime.h>

typedef unsigned int u32;
typedef unsigned long long u64;

#define R_ROUNDS 64
#define HID 256
#define BATCH 16384
#define RPW 4   // batch rows per wave

// ---------------------------------------------------------------------------
// FINAL (revert to round-9 best: 228.0 us, ~80% of stream-BW ceiling on the
// compulsory 1.1 GB of traffic; all latency-structure levers measured
// neutral -- see session journal R1-R10).
//
// GF(2) reduction of the reference:
//   s' = (floor(s@M^T + n)) mod 2, s,n in {0,1}, M in {-1,0,1}
//      = parity(popcount(s & (M!=0) row)) XOR n        (-1 == 1 mod 2)
//
// pi-order: lane l owns output bits {4l..4l+3}; packed u64 word k of the
// state has bit l = vector bit (4l+k). Noise/state/out are float4 per lane.
//
// Counted-drain sync (m201/HK pattern, minimal fencing):
//   per phase: {STAGE(r+2) 2 loads; LOADN(r+2) 4 loads; RUN(r);
//               s_waitcnt vmcnt(6); s_barrier; sched_barrier(0)}
// vmcnt(6) retires exactly the PREVIOUS phase's 6 VMEM ops, so every load
// gets ~2 phases in flight and the HBM queue never drains to zero.
// Quad-buffered LDS: stage->use distance 2, reuse distance 4.
// ---------------------------------------------------------------------------

// Pack ternary matrices -> pi-ordered, round-transposed bitmasks in d_ws.
// Round r's 8KB block: u32 P[r*2048 + t*256 + l*4 + q] = u32 (4h+q) of
// mask row (4l+i), where t = 2i+h; row u32 layout [W0lo,W0hi,...,W3lo,W3hi],
// W_k bit l = (M[row][4l+k] != 0).
__global__ __launch_bounds__(256) void pack_matrices_kernel(
        const float* __restrict__ M, u32* __restrict__ P) {
    const int lane = threadIdx.x & 63;
    const int gw   = (int)((blockIdx.x * blockDim.x + threadIdx.x) >> 6); // row 0..16383
    const int r    = gw >> 8;      // round
    const int jj   = gw & 255;     // row within round
    const float4 v = *(const float4*)(M + (size_t)gw * HID + 4 * lane);
    const u64 b0 = __ballot(v.x != 0.0f);
    const u64 b1 = __ballot(v.y != 0.0f);
    const u64 b2 = __ballot(v.z != 0.0f);
    const u64 b3 = __ballot(v.w != 0.0f);
    if (lane < 8) {
        const int w = lane;                 // u32-in-row index 0..7
        u64 bb = b0;
        if ((w >> 1) == 1) bb = b1;
        if ((w >> 1) == 2) bb = b2;
        if ((w >> 1) == 3) bb = b3;
        const u32 val = (w & 1) ? (u32)(bb >> 32) : (u32)bb;
        const int t = 2 * (jj & 3) + (w >> 2);          // chunk index 0..7
        P[r * 2048 + t * 256 + (jj >> 2) * 4 + (w & 3)] = val;
    }
}

__global__ __launch_bounds__(256, 4) void tenshash_kernel(
        const float* __restrict__ state,
        const u32*  __restrict__ pA,
        const float* __restrict__ noise,
        float* __restrict__ out) {
    const int lane = threadIdx.x & 63;
    const int warp = threadIdx.x >> 6;
    const int wave = (int)(blockIdx.x * 4 + warp);
    const int row0 = wave * RPW;

    __shared__ u32 smem[4][2048];   // 4 x 8KB mask buffers, reuse distance 4

    // ---- init state (pi-order): S_k[rw] bit l = state bit (4l+k) ----
    u64 S0[RPW], S1[RPW], S2[RPW], S3[RPW];
#pragma unroll
    for (int rw = 0; rw < RPW; ++rw) {
        const float4 v = *(const float4*)(state + (size_t)(row0 + rw) * HID + 4 * lane);
        S0[rw] = __ballot(v.x != 0.0f);
        S1[rw] = __ballot(v.y != 0.0f);
        S2[rw] = __ballot(v.z != 0.0f);
        S3[rw] = __ballot(v.w != 0.0f);
    }

    const float* no_l = noise + (size_t)row0 * (R_ROUNDS * HID) + 4 * lane;

    // Stage round r's 8KB (transposed layout: LINEAR both sides):
    // each of the 4 waves stages 2 of the 8 1KB chunks = 2 VMEM ops.
    auto STAGE = [&](int r, int b) {
        const char* g = (const char*)(pA + (size_t)r * 2048);
#pragma unroll
        for (int t = 2 * warp; t < 2 * warp + 2; ++t) {
            __builtin_amdgcn_global_load_lds(
                (const __attribute__((address_space(1))) void*)
                    (g + t * 1024 + lane * 16),
                (__attribute__((address_space(3))) void*)&smem[b][t * 256],
                16, 0, 0);
        }
    };
    auto LOADN = [&](float4* n, int r) {      // 4 VMEM ops
#pragma unroll
        for (int rw = 0; rw < RPW; ++rw)
            n[rw] = *(const float4*)(no_l + (size_t)rw * (R_ROUNDS * HID) + r * HID);
    };
    // i-outer RUN (8 live mask VGPRs): chunk t at uint4 slot t*64+lane;
    // a0/a1 = the 8 u32s of mask row 4l+i.
    auto RUN = [&](const u32* base, const float4* n) {
        const uint4* p = (const uint4*)base;
        u64 ns0[RPW], ns1[RPW], ns2[RPW], ns3[RPW];
#pragma unroll
        for (int i = 0; i < 4; ++i) {
            const uint4 a0 = p[((2 * i) << 6) + lane];
            const uint4 a1 = p[((2 * i + 1) << 6) + lane];
            const u64 W0 = (u64)a0.x | ((u64)a0.y << 32);
            const u64 W1 = (u64)a0.z | ((u64)a0.w << 32);
            const u64 W2 = (u64)a1.x | ((u64)a1.y << 32);
            const u64 W3 = (u64)a1.z | ((u64)a1.w << 32);
#pragma unroll
            for (int rw = 0; rw < RPW; ++rw) {
                const float nfv = (i == 0) ? n[rw].x : (i == 1) ? n[rw].y
                                : (i == 2) ? n[rw].z : n[rw].w;
                const u32 c = (u32)__popcll(W0 & S0[rw]) + (u32)__popcll(W1 & S1[rw])
                            + (u32)__popcll(W2 & S2[rw]) + (u32)__popcll(W3 & S3[rw])
                            + (u32)nfv;                    // exact: nfv in {0.0,1.0}
                const u64 nb = __ballot((c & 1u) != 0);
                if (i == 0) ns0[rw] = nb; else if (i == 1) ns1[rw] = nb;
                else if (i == 2) ns2[rw] = nb; else ns3[rw] = nb;
            }
        }
#pragma unroll
        for (int rw = 0; rw < RPW; ++rw) {
            S0[rw] = ns0[rw]; S1[rw] = ns1[rw];
            S2[rw] = ns2[rw]; S3[rw] = ns3[rw];
        }
    };

    float4 n0[RPW], n1[RPW], n2[RPW], n3[RPW];

    // ---- prologue: two phases' worth of loads; retire the first 6 ----
    STAGE(0, 0); LOADN(n0, 0);        // L_{-2}: 6 VMEM
    STAGE(1, 1); LOADN(n1, 1);        // L_{-1}: 6 VMEM
    asm volatile("s_waitcnt vmcnt(6)" ::: "memory");   // L_{-2} retired
    __builtin_amdgcn_s_barrier();
    __builtin_amdgcn_sched_barrier(0);

    // Phase k (round r+k): stage r+k+2 -> buf (k+2)&3, noise r+k+2 -> NLOAD;
    // compute round r+k from buf k / NUSE; retire previous phase's 6 loads.
#define PHASE(k, NUSE, NLOAD)                                            \
    {                                                                    \
        int rs = r + k + 2; if (rs > R_ROUNDS - 1) rs = R_ROUNDS - 1;    \
        STAGE(rs, (k + 2) & 3);                                          \
        LOADN(NLOAD, rs);                                                \
        RUN(&smem[k][0], NUSE);                                          \
        asm volatile("s_waitcnt vmcnt(6)" ::: "memory");                 \
        __builtin_amdgcn_s_barrier();                                    \
        __builtin_amdgcn_sched_barrier(0);                               \
    }

#pragma unroll 1
    for (int r = 0; r < R_ROUNDS; r += 4) {
        PHASE(0, n0, n2)
        PHASE(1, n1, n3)
        PHASE(2, n2, n0)
        PHASE(3, n3, n1)
    }
#undef PHASE

    // ---- unpack final state, float4 stores ----
#pragma unroll
    for (int rw = 0; rw < RPW; ++rw) {
        float4 o;
        o.x = (float)((u32)(S0[rw] >> lane) & 1u);
        o.y = (float)((u32)(S1[rw] >> lane) & 1u);
        o.z = (float)((u32)(S2[rw] >> lane) & 1u);
        o.w = (float)((u32)(S3[rw] >> lane) & 1u);
        *(float4*)(out + (size_t)(row0 + rw) * HID + 4 * lane) = o;
    }
}

extern "C" void kernel_launch(void* const* d_in, const int* in_sizes, int n_in,
                              void* d_out, int out_size, void* d_ws, size_t ws_size,
                              hipStream_t stream) {
    const float* state = (const float*)d_in[0];
    const float* mats  = (const float*)d_in[1];
    const float* noise = (const float*)d_in[2];
    float* out         = (float*)d_out;
    u32* pA            = (u32*)d_ws;              // 512 KB packed masks

    pack_matrices_kernel<<<(R_ROUNDS * HID) / 4, 256, 0, stream>>>(mats, pA);

    const int blocks = (BATCH / RPW) / 4;         // 1024 blocks x 4 waves
    tenshash_kernel<<<blocks, 256, 0, stream>>>(state, pA, noise, out);
}